// Round 2
// baseline (3528.223 us; speedup 1.0000x reference)
//
#include <hip/hip_runtime.h>
#include <hip/hip_bf16.h>
#include <math.h>

// T=128, B=32, D=512, H=512, N=64, A=32, TAU=1
#define NTHR  512
#define NBLK  224              // 32 BC blocks + 192 GEMM blocks
#define HTXS  19456            // hTx buffer stride (2*9216 + pad)

// ---- flag area (int offsets into d_ws), LINE-SPACED (r8-proven) ----
// hflag[b] = bar[b*32]           (BC b sc1-stores t+1; own 128B line)
// wflag[g] = bar[1024 + g*32]    (GEMM block g sc1-stores t+1)
//   g<64    "def":  cols [512,1536)  fp32 K=512 (vA/vB path)
//   64..191 "late": cols [1536,4608) bf16 K=512 (gate path), 48 cols/blk
// crit (cols 0:512) is now computed LOCALLY by each BC block: it depends
// only on batch-local h/lu, so the publish->GEMM->oc->BC round trip for
// the argmax path is gone.  Nobody reads hTx rows 512:576 anymore.
#define OFF_HTX  8192                       // hTx_all: [129][2][576][16]
#define OFF_OC   (OFF_HTX + 129*HTXS)       // oc: [32][4608] (cols 512: used)
#define OFF_HNEW (OFF_OC + 32*4608)         // hnew_part: [32][64][512]
#define OFF_WHH  (OFF_HNEW + 32*64*512)     // whh_part: [32][64][1536]
#define OFF_C0   (OFF_WHH + 32*64*1536)     // c0: [1536]
#define OFF_WCAT (OFF_C0 + 1536)            // Wcat: [576][4608] fp32 row-major
#define OFF_WB16 (OFF_WCAT + 576*4608)      // Wb16: [512][3072] bf16 (ushort)
#define OFF_P1   (OFF_WB16 + 512*1536)      // P1: [4096][1536]
#define OFF_P2   (OFF_P1 + 4096*1536)       // P2: [4096][512]
// end ≈ 75.1 MB (< 76.5 MB known-good)

// sc1 (agent-scope): bypass per-XCD L2, coherent at LLC. Flags, oc, hTx
// writes are sc1; hTx READS are normal cached loads (rotating buffers).
__device__ __forceinline__ float cohLoad(const float* p) {
  return __hip_atomic_load(p, __ATOMIC_RELAXED, __HIP_MEMORY_SCOPE_AGENT);
}
__device__ __forceinline__ void cohStore(float* p, float v) {
  __hip_atomic_store(p, v, __ATOMIC_RELAXED, __HIP_MEMORY_SCOPE_AGENT);
}
__device__ __forceinline__ int cohLoadI(const int* p) {
  return __hip_atomic_load(p, __ATOMIC_RELAXED, __HIP_MEMORY_SCOPE_AGENT);
}
__device__ __forceinline__ void cohStoreI(int* p, int v) {
  __hip_atomic_store(p, v, __ATOMIC_RELAXED, __HIP_MEMORY_SCOPE_AGENT);
}
__device__ __forceinline__ float bf2f(unsigned short u) {
  return __uint_as_float(((unsigned int)u) << 16);
}

// ---------------------------------------------------------------------------
// Generic tiled fp32 GEMM (pre-pass only)
// ---------------------------------------------------------------------------
__global__ __launch_bounds__(256) void gemm_f32(
    const float* __restrict__ A, const float* __restrict__ B,
    const float* __restrict__ bias, float* __restrict__ C,
    int M, int N, int K, int lda, int ldb, int ldc)
{
  __shared__ float As[16][132];
  __shared__ float Bs[16][64];
  const int bm = blockIdx.x * 128, bn = blockIdx.y * 64;
  const int tid = threadIdx.x;
  const int tx = tid & 15, ty = tid >> 4;
  float acc[8][4];
  #pragma unroll
  for (int i = 0; i < 8; ++i)
    #pragma unroll
    for (int j = 0; j < 4; ++j) acc[i][j] = 0.f;

  for (int kt = 0; kt < K; kt += 16) {
    #pragma unroll
    for (int i = 0; i < 2; ++i) {
      int li = tid + i*256;
      int r = li >> 2, q = li & 3;
      float4 a4 = *(const float4*)(A + (size_t)(bm + r)*lda + kt + q*4);
      As[q*4+0][r] = a4.x; As[q*4+1][r] = a4.y;
      As[q*4+2][r] = a4.z; As[q*4+3][r] = a4.w;
    }
    {
      int k = tid >> 4, nq = tid & 15;
      *(float4*)(&Bs[k][nq*4]) = *(const float4*)(B + (size_t)(kt + k)*ldb + bn + nq*4);
    }
    __syncthreads();
    #pragma unroll
    for (int kk = 0; kk < 16; ++kk) {
      float av[8], bv[4];
      *(float4*)(av)   = *(const float4*)(&As[kk][ty*8]);
      *(float4*)(av+4) = *(const float4*)(&As[kk][ty*8+4]);
      *(float4*)(bv)   = *(const float4*)(&Bs[kk][tx*4]);
      #pragma unroll
      for (int i = 0; i < 8; ++i)
        #pragma unroll
        for (int j = 0; j < 4; ++j) acc[i][j] += av[i]*bv[j];
    }
    __syncthreads();
  }
  #pragma unroll
  for (int i = 0; i < 8; ++i) {
    int m = bm + ty*8 + i;
    #pragma unroll
    for (int j = 0; j < 4; ++j) {
      int n = bn + tx*4 + j;
      float v = acc[i][j];
      if (bias) v += bias[n];
      C[(size_t)m*ldc + n] = v;
    }
  }
}

// ---------------------------------------------------------------------------
// Setup: Wcat (row-major [576][4608]) static parts + c0.
// ---------------------------------------------------------------------------
__global__ __launch_bounds__(512) void setup_kernel(
    const float* __restrict__ W_hm, const float* __restrict__ fc2_w,
    const float* __restrict__ W_um, const float* __restrict__ W_hh,
    const float* __restrict__ bias, const float* __restrict__ fc2_b,
    float* __restrict__ Wcat, float* __restrict__ c0)
{
  const int idx = blockIdx.x * 512 + threadIdx.x;
  if (idx < 512*1536) {                       // rows 0:512, cols 0:1536
    int k = idx / 1536, c = idx % 1536;
    float v;
    if (c < 512)       v = W_hm[k*512 + c];
    else if (c < 1024) v = fc2_w[k*512 + (c-512)];
    else               v = fc2_w[(size_t)(512+k)*512 + (c-1024)];
    Wcat[(size_t)k*4608 + c] = v;
    return;
  }
  int i = idx - 512*1536;
  if (i < 64*4608) {                          // rows 512:576
    int k2 = i / 4608, c = i % 4608;
    Wcat[(size_t)(512+k2)*4608 + c] = (c < 512) ? W_um[k2*512 + c] : 0.f;
    return;
  }
  i -= 64*4608;
  if (i < 1536) {                             // c0 = fc2_b@W_hh + bias_hh
    float s = bias[1536 + i];
    for (int m = 0; m < 512; ++m) s += fc2_b[m] * W_hh[(size_t)m*1536 + i];
    c0[i] = s;
  }
}

// Wb16[k][3072] = bf16(Wcat[k][1536+c]), k<512 — runs after M_A/M_B GEMMs.
__global__ __launch_bounds__(512) void cvt_kernel(
    const float* __restrict__ Wcat, unsigned short* __restrict__ Wb16)
{
  const int idx = blockIdx.x * 512 + threadIdx.x;   // 512*3072
  const int k = idx / 3072, c = idx % 3072;
  __hip_bfloat16 h = __float2bfloat16(Wcat[(size_t)k*4608 + 1536 + c]);
  Wb16[idx] = *(unsigned short*)&h;
}

// ---------------------------------------------------------------------------
// Persistent scan. Blocks 0..31: BC (batch, incl LOCAL crit slice).
// Blocks 32..223: GEMM.  gb = bid-32:
//   gb<64   def:  cols [512+cg*32,+32)   fp32 K=512 (8 segs x 64k)
//   gb<192  late: cols [1536+cg*48,+48)  bf16 K=512 (8 segs x 64k)
// Wave-private staging (rows [wv*64,+64)) — no stage barrier needed.
// BC local crit: oc0[c] = sum_k hx[k]*Wcat[k][c], hx = {h(t), lu(t)} held
// in LDS; 8 waves split K=576, lane owns 8 cols; LDS reduce.  The argmax
// chain never leaves the CU.  def+late (192 flags) ride the whole window.
// ---------------------------------------------------------------------------
__global__ __launch_bounds__(NTHR, 1) void persist_kernel(
    const float* __restrict__ P1, const float* __restrict__ P2,
    const float* __restrict__ Wcat, const unsigned short* __restrict__ Wb16,
    float* __restrict__ oc, float* __restrict__ hTx_all,
    float* __restrict__ hnew_part, float* __restrict__ whh_part,
    const float* __restrict__ c0, const float* __restrict__ fc1_w,
    const float* __restrict__ fc1_b, const float* __restrict__ fc2_b,
    const float* __restrict__ u_noise, const int* __restrict__ length,
    const float* __restrict__ fc_w, const float* __restrict__ fc_b,
    float* __restrict__ out, int* __restrict__ bar)
{
  __shared__ float smem[14400];  // GEMM: hxs[8192]+red; late red=6208 -> 14400
  const int bid = blockIdx.x;
  const int tid = threadIdx.x;
  const int wv = tid >> 6, lane = tid & 63;

  if (bid >= 32) {
    // ================= GEMM blocks =================
    const int gb = bid - 32;             // 0..191
    const int bg = gb & 1;               // batch half
    float* hxs = smem;                   // k-major [512][16] (this batch-half)
    const int s  = tid >> 6;             // K-seg 0..7 (= wave)
    const int bq = tid & 3;
    const int kbase = s * 64;

    if (gb < 64) {
      // ---- def: cols [512+cg*32,+32), fp32 K=512 ----
      const int cg = gb >> 1;
      const int colbase = 512 + cg * 32;
      const int c = (tid >> 2) & 15;     // 2 cols each
      float* red = smem + 8192;          // [8][520]
      for (int t = 0; t < 128; ++t) {
        if (tid < 16) {
          while (cohLoadI(&bar[(bg*16 + tid)*32]) < t) __builtin_amdgcn_s_sleep(1);
        }
        __syncthreads();
        {  // wave-private stage: rows [wv*64,+64) = 256 float4
          const float4* src4 = (const float4*)(hTx_all + (size_t)t*HTXS + bg*9216) + wv*256;
          float4* dst4 = (float4*)hxs + wv*256;
          for (int i = lane; i < 256; i += 64) dst4[i] = src4[i];
        }
        float acc[4][2] = {{0.f,0.f},{0.f,0.f},{0.f,0.f},{0.f,0.f}};
        const float* hp = hxs + kbase*16 + bq*4;
        const float* wp = Wcat + (size_t)kbase*4608 + colbase + c*2;
        #pragma unroll 4
        for (int kk = 0; kk < 64; ++kk) {
          float4 h4 = *(const float4*)(hp); hp += 16;
          float w0 = wp[0], w1 = wp[1]; wp += 4608;
          acc[0][0] += h4.x*w0; acc[0][1] += h4.x*w1;
          acc[1][0] += h4.y*w0; acc[1][1] += h4.y*w1;
          acc[2][0] += h4.z*w0; acc[2][1] += h4.z*w1;
          acc[3][0] += h4.w*w0; acc[3][1] += h4.w*w1;
        }
        {
          float* rp = red + s*520 + (bq*4)*32 + c*2;
          #pragma unroll
          for (int bi = 0; bi < 4; ++bi)
            *(float2*)(rp + bi*32) = make_float2(acc[bi][0], acc[bi][1]);
        }
        __syncthreads();
        {                                 // 16b x 32c, one per thread
          float ssum = 0.f;
          #pragma unroll
          for (int w = 0; w < 8; ++w) ssum += red[w*520 + tid];
          int b16 = tid >> 5, cc = tid & 31;
          cohStore(&oc[(size_t)(bg*16 + b16)*4608 + colbase + cc], ssum);
        }
        __syncthreads();                 // drain sc1 stores
        if (tid == 0) cohStoreI(&bar[1024 + gb*32], t + 1);
      }
    } else {
      // ---- late: cols [1536+cg*48,+48), bf16 K=512 ----
      const int cg = (gb - 64) >> 1;
      const int colbase = 1536 + cg * 48;
      const int c = (tid >> 2) & 15;     // 3 cols each
      float* red = smem + 8192;          // [8][776]
      for (int t = 0; t < 128; ++t) {
        if (tid < 16) {
          while (cohLoadI(&bar[(bg*16 + tid)*32]) < t) __builtin_amdgcn_s_sleep(1);
        }
        __syncthreads();
        {  // wave-private stage: rows [wv*64,+64) = 256 float4
          const float4* src4 = (const float4*)(hTx_all + (size_t)t*HTXS + bg*9216) + wv*256;
          float4* dst4 = (float4*)hxs + wv*256;
          for (int i = lane; i < 256; i += 64) dst4[i] = src4[i];
        }
        float acc[4][3] = {{0.f,0.f,0.f},{0.f,0.f,0.f},{0.f,0.f,0.f},{0.f,0.f,0.f}};
        const float* hp = hxs + kbase*16 + bq*4;
        const unsigned short* wp = Wb16 + (size_t)kbase*3072 + (colbase - 1536) + c*3;
        #pragma unroll 4
        for (int kk = 0; kk < 64; ++kk) {
          float4 h4 = *(const float4*)(hp); hp += 16;
          float w0 = bf2f(wp[0]), w1 = bf2f(wp[1]), w2 = bf2f(wp[2]); wp += 3072;
          acc[0][0] += h4.x*w0; acc[0][1] += h4.x*w1; acc[0][2] += h4.x*w2;
          acc[1][0] += h4.y*w0; acc[1][1] += h4.y*w1; acc[1][2] += h4.y*w2;
          acc[2][0] += h4.z*w0; acc[2][1] += h4.z*w1; acc[2][2] += h4.z*w2;
          acc[3][0] += h4.w*w0; acc[3][1] += h4.w*w1; acc[3][2] += h4.w*w2;
        }
        {
          float* rp = red + s*776 + (bq*4)*48 + c*3;
          #pragma unroll
          for (int bi = 0; bi < 4; ++bi) {
            rp[bi*48 + 0] = acc[bi][0];
            rp[bi*48 + 1] = acc[bi][1];
            rp[bi*48 + 2] = acc[bi][2];
          }
        }
        __syncthreads();
        for (int i = tid; i < 768; i += NTHR) {   // 16b x 48c
          float ssum = 0.f;
          #pragma unroll
          for (int w = 0; w < 8; ++w) ssum += red[w*776 + i];
          int b16 = i / 48, cc = i - b16*48;
          cohStore(&oc[(size_t)(bg*16 + b16)*4608 + colbase + cc], ssum);
        }
        __syncthreads();                 // drain sc1 stores
        if (tid == 0) cohStoreI(&bar[1024 + gb*32], t + 1);
      }
    }
  } else {
    // ================= BC block: batch b =================
    const int b = bid;
    const int lenb = length[b];
    float hcur = 0.f;
    float usage_r = -99999.f;            // valid for tid<64
    int jprev = 0;                       // thread-0 only
    // smem layout (floats):
    float* sh_hx  = smem;                // [576] h(t) | lu(t)
    float* sh_red = smem + 576;          // [8][512] oc0 wave partials
    float* sh_th  = smem + 4672;         // [512]
    float* sh_p   = smem + 5184;         // [512] fc1 / out partials
    int*   flg    = (int*)(smem + 5700);
    const float c0r = c0[tid], c0z = c0[512 + tid], c0n = c0[1024 + tid];
    const float fc2bv = fc2_b[tid];
    const float f1b = (tid < 64) ? fc1_b[tid] : 0.f;
    const int n_ = tid & 63, kg_ = tid >> 6;
    const float* fw = fc1_w + (size_t)kg_*64*64 + n_;

    if (tid < 576) sh_hx[tid] = 0.f;     // h(0)=0, lu(0)=sigmoid(-inf)=0
    __syncthreads();

    for (int t = 0; t < 128; ++t) {
      const int t32b = t*32 + b;
      // prefetch step inputs (independent of everything)
      const float* p1p = P1 + (size_t)t32b*1536;
      float p1r = p1p[tid], p1z = p1p[512 + tid], p1n = p1p[1024 + tid];
      float p2v = P2[(size_t)t32b*512 + tid];
      float uval = (tid < 64) ? u_noise[(size_t)t32b*64 + tid] : 0.f;

      // ---- LOCAL crit slice: oc0 = hx(t) @ Wcat[:,0:512] ----
      // wave wv: k in [wv*72,+72); lane owns cols [lane*8,+8)
      {
        float a8[8];
        #pragma unroll
        for (int i = 0; i < 8; ++i) a8[i] = 0.f;
        const float* wrow = Wcat + (size_t)(wv*72)*4608 + lane*8;
        const float* hxk = sh_hx + wv*72;
        #pragma unroll 2
        for (int kq = 0; kq < 18; ++kq) {
          float4 h4 = *(const float4*)(hxk + kq*4);
          #pragma unroll
          for (int u = 0; u < 4; ++u) {
            float hk = (u == 0) ? h4.x : (u == 1) ? h4.y : (u == 2) ? h4.z : h4.w;
            float4 wa = *(const float4*)(wrow);
            float4 wb = *(const float4*)(wrow + 4);
            wrow += 4608;
            a8[0] += hk*wa.x; a8[1] += hk*wa.y; a8[2] += hk*wa.z; a8[3] += hk*wa.w;
            a8[4] += hk*wb.x; a8[5] += hk*wb.y; a8[6] += hk*wb.z; a8[7] += hk*wb.w;
          }
        }
        *(float4*)(&sh_red[wv*512 + lane*8])     = make_float4(a8[0], a8[1], a8[2], a8[3]);
        *(float4*)(&sh_red[wv*512 + lane*8 + 4]) = make_float4(a8[4], a8[5], a8[6], a8[7]);
      }
      __syncthreads();
      {
        float oc0 = 0.f;
        #pragma unroll
        for (int w = 0; w < 8; ++w) oc0 += sh_red[w*512 + tid];
        sh_th[tid] = tanhf(p2v + oc0);   // th
      }
      __syncthreads();
      {                                  // fc1 partial dots
        float sdot = 0.f;
        #pragma unroll 8
        for (int k = 0; k < 64; ++k) sdot += sh_th[kg_*64 + k] * fw[(size_t)k*64];
        sh_p[tid] = sdot;
      }
      __syncthreads();
      if (tid < 64) {                    // logits + Gumbel + wave argmax
        float l = f1b;
        #pragma unroll
        for (int kg = 0; kg < 8; ++kg) l += sh_p[kg*64 + tid];
        l += -logf(1e-20f - logf(1e-20f + uval));
        float best = l; int idx = tid;
        #pragma unroll
        for (int off = 32; off >= 1; off >>= 1) {
          float ob = __shfl_xor(best, off);
          int   oi = __shfl_xor(idx,  off);
          if (ob > best || (ob == best && oi < idx)) { best = ob; idx = oi; }
        }
        if (tid == 0) {
          flg[0] = idx;
          flg[1] = (t < 64) ? t : jprev;
          jprev = idx;
        }
      }
      // ---- wait DEF + LATE blocks (g 0..191): 192 line-spaced flags ----
      if (tid < 192) {
        while (cohLoadI(&bar[1024 + tid*32]) < t + 1) __builtin_amdgcn_s_sleep(1);
      }
      __syncthreads();
      const int jj = flg[0], ss = flg[1];
      const float* ocb = oc + (size_t)b*4608;
      float vA   = cohLoad(ocb + 512  + tid);
      float vB   = cohLoad(ocb + 1024 + tid);
      float vAW0 = cohLoad(ocb + 1536 + tid);
      float vAW1 = cohLoad(ocb + 2048 + tid);
      float vAW2 = cohLoad(ocb + 2560 + tid);
      float vBW0 = cohLoad(ocb + 3072 + tid);
      float vBW1 = cohLoad(ocb + 3584 + tid);
      float vBW2 = cohLoad(ocb + 4096 + tid);
      float hnp, w0, w1, w2;
      if (jj == ss) { hnp = vA; w0 = vAW0; w1 = vAW1; w2 = vAW2; }
      else {
        hnp = hnew_part[(size_t)(b*64 + jj)*512 + tid];
        const float* wpp = whh_part + (size_t)(b*64 + jj)*1536;
        w0 = wpp[tid]; w1 = wpp[512 + tid]; w2 = wpp[1024 + tid];
      }
      float h_new = hnp + vB + fc2bv;
      float wh_r = w0 + vBW0 + c0r;
      float wh_z = w1 + vBW1 + c0z;
      float wh_n = w2 + vBW2 + c0n;
      float r  = 1.f / (1.f + expf(-(p1r + wh_r)));
      float z  = 1.f / (1.f + expf(-(p1z + wh_z)));
      float nn = tanhf(p1n + r*wh_n);
      float h1 = (1.f - z)*nn + z*h_new;
      if (t >= lenb) h1 = hcur;
      hcur = h1;
      // publish h(t+1) via sc1 (k-major [512][16], half b>>4); lu stays local
      float* hw = hTx_all + (size_t)(t + 1)*HTXS + (b >> 4)*9216;
      cohStore(&hw[tid*16 + (b & 15)], h1);
      sh_hx[tid] = h1;
      if (tid < 64) {
        float un = (usage_r - 1.f) * (tid == jj ? 0.f : 1.f);
        usage_r = un;
        sh_hx[512 + tid] = 1.f / (1.f + expf(-un));
      }
      __syncthreads();                   // drain sc1 stores + order sh_hx
      if (tid == 0) cohStoreI(&bar[b*32], t + 1);
      // ---- off critical path: slot caches + output projection ----
      hnew_part[(size_t)(b*64 + ss)*512 + tid] = vA;
      float* wps = whh_part + (size_t)(b*64 + ss)*1536;
      wps[tid] = vAW0; wps[512 + tid] = vAW1; wps[1024 + tid] = vAW2;
      {
        int a = tid & 31, jg = tid >> 5;
        float sp = 0.f;
        #pragma unroll 8
        for (int jx = 0; jx < 32; ++jx)
          sp += sh_hx[jg*32 + jx] * fc_w[(size_t)(jg*32 + jx)*32 + a];
        sh_p[tid] = sp;
      }
      __syncthreads();
      if (tid < 32) {
        float s2 = fc_b[tid];
        #pragma unroll
        for (int jg = 0; jg < 16; ++jg) s2 += sh_p[jg*32 + tid];
        out[(size_t)t32b*32 + tid] = s2;
      }
    }
  }
}

// ---------------------------------------------------------------------------
extern "C" void kernel_launch(void* const* d_in, const int* in_sizes, int n_in,
                              void* d_out, int out_size, void* d_ws, size_t ws_size,
                              hipStream_t stream)
{
  const float* x      = (const float*)d_in[0];
  const int*   length = (const int*)  d_in[1];
  const float* u_nois = (const float*)d_in[2];
  const float* W_ih   = (const float*)d_in[3];
  const float* W_hh   = (const float*)d_in[4];
  const float* bias   = (const float*)d_in[5];
  const float* W_im   = (const float*)d_in[6];
  const float* W_hm   = (const float*)d_in[7];
  const float* W_um   = (const float*)d_in[8];
  const float* fc1_w  = (const float*)d_in[9];
  const float* fc1_b  = (const float*)d_in[10];
  const float* fc2_w  = (const float*)d_in[11];
  const float* fc2_b  = (const float*)d_in[12];
  const float* fc_w   = (const float*)d_in[13];
  const float* fc_b   = (const float*)d_in[14];
  float* out = (float*)d_out;

  float* ws   = (float*)d_ws;
  int*   bar  = (int*)d_ws;
  float* hTx  = ws + OFF_HTX;
  float* oc   = ws + OFF_OC;
  float* hnew = ws + OFF_HNEW;
  float* whh  = ws + OFF_WHH;
  float* c0   = ws + OFF_C0;
  float* Wcat = ws + OFF_WCAT;
  unsigned short* Wb16 = (unsigned short*)(ws + OFF_WB16);
  float* P1   = ws + OFF_P1;
  float* P2   = ws + OFF_P2;

  // zero: flag words + hTx buffer 0 (h=0); slot caches (mem=0)
  hipMemsetAsync(d_ws, 0, (size_t)(OFF_HTX + HTXS) * sizeof(float), stream);
  hipMemsetAsync(hnew, 0, (size_t)(32*64*512 + 32*64*1536) * sizeof(float), stream);

  setup_kernel<<<2115, 512, 0, stream>>>(W_hm, fc2_w, W_um, W_hh, bias, fc2_b,
                                         Wcat, c0);

  // M_A = fc2_A@W_hh -> Wcat cols 1536:3072 ; M_B = fc2_B@W_hh -> 3072:4608
  { dim3 g(4, 24);
    gemm_f32<<<g, 256, 0, stream>>>(fc2_w,                   W_hh, nullptr, Wcat + 1536,
                                    512, 1536, 512, 512, 1536, 4608);
    gemm_f32<<<g, 256, 0, stream>>>(fc2_w + (size_t)512*512, W_hh, nullptr, Wcat + 3072,
                                    512, 1536, 512, 512, 1536, 4608); }
  // bf16 compaction of the gate-path composite weights
  cvt_kernel<<<3072, 512, 0, stream>>>(Wcat, Wb16);
  // P1 = x@W_ih + bias_ih ; P2 = x@W_im
  { dim3 g(32, 24);
    gemm_f32<<<g, 256, 0, stream>>>(x, W_ih, bias, P1, 4096, 1536, 512, 512, 1536, 1536); }
  { dim3 g(32, 8);
    gemm_f32<<<g, 256, 0, stream>>>(x, W_im, nullptr, P2, 4096, 512, 512, 512, 512, 512); }

  persist_kernel<<<NBLK, NTHR, 0, stream>>>(P1, P2, Wcat, Wb16, oc, hTx, hnew,
                                            whh, c0, fc1_w, fc1_b, fc2_b,
                                            u_nois, length, fc_w, fc_b, out, bar);
}

// Round 4
// 1949.236 us; speedup vs baseline: 1.8101x; 1.8101x over previous
//
#include <hip/hip_runtime.h>
#include <hip/hip_bf16.h>
#include <math.h>

// T=128, B=32, D=512, H=512, N=64, A=32, TAU=1
#define NTHR  512
#define NBLK  256              // 32 BC blocks + 224 GEMM blocks (all CUs)
#define HTXS  18432            // hTx stride per t: 32 batches x 576 (b-major)

// ---- flag area (int offsets into d_ws), LINE-SPACED (r8-proven) ----
// hflag[b] = bar[b*32]           (BC b sc1-stores t+1; own 128B line)
// wflag[g] = bar[1024 + g*32]    (GEMM block g sc1-stores t+1)
//   g<64    "crit": cols [0,512)    fp32 K=576 (th path -> argmax)
//   64..127 "def":  cols [512,1536) fp32 K=512 (vA/vB path, argmax slack)
//   128..223 "late": cols [1536,4608) bf16 K=512, 64 cols/blk  <-- r3 bug:
//   was 32 cols/blk covering only [1536,3072); cols [3072,4608) never
//   written -> garbage vBW -> absmax blowup. Fixed: cg*64, 48 groups.
// hTx is b-major [129][32][576]: BC publish = 576 contiguous coalesced
// stores; GEMM inner loop reads h 4-k-per-ds_read_b128.
// Weights stay ROW-major, partitioned per block (L2-private; r2 lesson:
// replicating weight slices across blocks explodes FETCH/LLC).
#define OFF_HTX  8192                       // hTx_all: [129][32][576]
#define OFF_OC   (OFF_HTX + 129*HTXS)       // oc: [32][4608]
#define OFF_HNEW (OFF_OC + 32*4608)         // hnew_part: [32][64][512]
#define OFF_WHH  (OFF_HNEW + 32*64*512)     // whh_part: [32][64][1536]
#define OFF_C0   (OFF_WHH + 32*64*1536)     // c0: [1536]
#define OFF_WCAT (OFF_C0 + 1536)            // Wcat: [576][4608] fp32 row-major
#define OFF_WB16 (OFF_WCAT + 576*4608)      // Wb16: [512][3072] bf16 (ushort)
#define OFF_P1   (OFF_WB16 + 512*1536)      // P1: [4096][1536]
#define OFF_P2   (OFF_P1 + 4096*1536)       // P2: [4096][512]
// end ≈ 74.2 MB (< 75.1 MB known-good)

// sc1 (agent-scope): bypass per-XCD L2, coherent at LLC. Flags, oc, hTx
// writes are sc1; hTx READS are normal cached loads (rotating buffers).
__device__ __forceinline__ float cohLoad(const float* p) {
  return __hip_atomic_load(p, __ATOMIC_RELAXED, __HIP_MEMORY_SCOPE_AGENT);
}
__device__ __forceinline__ void cohStore(float* p, float v) {
  __hip_atomic_store(p, v, __ATOMIC_RELAXED, __HIP_MEMORY_SCOPE_AGENT);
}
__device__ __forceinline__ int cohLoadI(const int* p) {
  return __hip_atomic_load(p, __ATOMIC_RELAXED, __HIP_MEMORY_SCOPE_AGENT);
}
__device__ __forceinline__ void cohStoreI(int* p, int v) {
  __hip_atomic_store(p, v, __ATOMIC_RELAXED, __HIP_MEMORY_SCOPE_AGENT);
}
__device__ __forceinline__ float bf2f(unsigned short u) {
  return __uint_as_float(((unsigned int)u) << 16);
}

// ---------------------------------------------------------------------------
// Generic tiled fp32 GEMM (pre-pass only)
// ---------------------------------------------------------------------------
__global__ __launch_bounds__(256) void gemm_f32(
    const float* __restrict__ A, const float* __restrict__ B,
    const float* __restrict__ bias, float* __restrict__ C,
    int M, int N, int K, int lda, int ldb, int ldc)
{
  __shared__ float As[16][132];
  __shared__ float Bs[16][64];
  const int bm = blockIdx.x * 128, bn = blockIdx.y * 64;
  const int tid = threadIdx.x;
  const int tx = tid & 15, ty = tid >> 4;
  float acc[8][4];
  #pragma unroll
  for (int i = 0; i < 8; ++i)
    #pragma unroll
    for (int j = 0; j < 4; ++j) acc[i][j] = 0.f;

  for (int kt = 0; kt < K; kt += 16) {
    #pragma unroll
    for (int i = 0; i < 2; ++i) {
      int li = tid + i*256;
      int r = li >> 2, q = li & 3;
      float4 a4 = *(const float4*)(A + (size_t)(bm + r)*lda + kt + q*4);
      As[q*4+0][r] = a4.x; As[q*4+1][r] = a4.y;
      As[q*4+2][r] = a4.z; As[q*4+3][r] = a4.w;
    }
    {
      int k = tid >> 4, nq = tid & 15;
      *(float4*)(&Bs[k][nq*4]) = *(const float4*)(B + (size_t)(kt + k)*ldb + bn + nq*4);
    }
    __syncthreads();
    #pragma unroll
    for (int kk = 0; kk < 16; ++kk) {
      float av[8], bv[4];
      *(float4*)(av)   = *(const float4*)(&As[kk][ty*8]);
      *(float4*)(av+4) = *(const float4*)(&As[kk][ty*8+4]);
      *(float4*)(bv)   = *(const float4*)(&Bs[kk][tx*4]);
      #pragma unroll
      for (int i = 0; i < 8; ++i)
        #pragma unroll
        for (int j = 0; j < 4; ++j) acc[i][j] += av[i]*bv[j];
    }
    __syncthreads();
  }
  #pragma unroll
  for (int i = 0; i < 8; ++i) {
    int m = bm + ty*8 + i;
    #pragma unroll
    for (int j = 0; j < 4; ++j) {
      int n = bn + tx*4 + j;
      float v = acc[i][j];
      if (bias) v += bias[n];
      C[(size_t)m*ldc + n] = v;
    }
  }
}

// ---------------------------------------------------------------------------
// Setup: Wcat (row-major [576][4608]) static parts + c0.
// ---------------------------------------------------------------------------
__global__ __launch_bounds__(512) void setup_kernel(
    const float* __restrict__ W_hm, const float* __restrict__ fc2_w,
    const float* __restrict__ W_um, const float* __restrict__ W_hh,
    const float* __restrict__ bias, const float* __restrict__ fc2_b,
    float* __restrict__ Wcat, float* __restrict__ c0)
{
  const int idx = blockIdx.x * 512 + threadIdx.x;
  if (idx < 512*1536) {                       // rows 0:512, cols 0:1536
    int k = idx / 1536, c = idx % 1536;
    float v;
    if (c < 512)       v = W_hm[k*512 + c];
    else if (c < 1024) v = fc2_w[k*512 + (c-512)];
    else               v = fc2_w[(size_t)(512+k)*512 + (c-1024)];
    Wcat[(size_t)k*4608 + c] = v;
    return;
  }
  int i = idx - 512*1536;
  if (i < 64*4608) {                          // rows 512:576
    int k2 = i / 4608, c = i % 4608;
    Wcat[(size_t)(512+k2)*4608 + c] = (c < 512) ? W_um[k2*512 + c] : 0.f;
    return;
  }
  i -= 64*4608;
  if (i < 1536) {                             // c0 = fc2_b@W_hh + bias_hh
    float s = bias[1536 + i];
    for (int m = 0; m < 512; ++m) s += fc2_b[m] * W_hh[(size_t)m*1536 + i];
    c0[i] = s;
  }
}

// Wb16[k][3072] = bf16(Wcat[k][1536+c]), k<512 — runs after M_A/M_B GEMMs.
__global__ __launch_bounds__(512) void cvt_kernel(
    const float* __restrict__ Wcat, unsigned short* __restrict__ Wb16)
{
  const int idx = blockIdx.x * 512 + threadIdx.x;   // 512*3072
  const int k = idx / 3072, c = idx % 3072;
  __hip_bfloat16 h = __float2bfloat16(Wcat[(size_t)k*4608 + 1536 + c]);
  Wb16[idx] = *(unsigned short*)&h;
}

// ---------------------------------------------------------------------------
// Persistent scan. Blocks 0..31: BC (batch). Blocks 32..255: GEMM.
//   gb = bid-32, bg = gb&1 (batch half):
//     gb<64   crit: cols [cg*16,+16)        fp32 K=576, cg=gb>>1
//     gb<128  def:  cols [512+cg*32,+32)    fp32 K=512, cg=(gb-64)>>1
//     gb<224  late: cols [1536+cg*64,+64)   bf16 K=512, cg=(gb-128)>>1
// LDS hxs is b-major [16][K+4pad]; stage = linear coalesced copy.
// Inner loop: 1 ds_read_b128 covers 4 k's; weights float4/uint4 row-major
// (16 batch lanes broadcast-coalesce each weight load). Seg-reduce via LDS.
// ---------------------------------------------------------------------------
__global__ __launch_bounds__(NTHR, 1) void persist_kernel(
    const float* __restrict__ P1, const float* __restrict__ P2,
    const float* __restrict__ Wcat, const unsigned short* __restrict__ Wb16,
    float* __restrict__ oc, float* __restrict__ hTx_all,
    float* __restrict__ hnew_part, float* __restrict__ whh_part,
    const float* __restrict__ c0, const float* __restrict__ fc1_w,
    const float* __restrict__ fc1_b, const float* __restrict__ fc2_b,
    const float* __restrict__ u_noise, const int* __restrict__ length,
    const float* __restrict__ fc_w, const float* __restrict__ fc_b,
    float* __restrict__ out, int* __restrict__ bar)
{
  __shared__ float smem[13376];  // hxs 16x580=9280 + red up to 4x1024=4096
  const int bid = blockIdx.x;
  const int tid = threadIdx.x;

  if (bid >= 32) {
    // ================= GEMM blocks =================
    const int gb = bid - 32;             // 0..223
    const int bg = gb & 1;               // batch half
    const int b  = tid & 15;             // batch within half
    float* hxs = smem;
    float* red = smem + 9280;

    if (gb < 64) {
      // ---- crit: cols [cg*16,+16), fp32 K=576, 8 segs x 72 ----
      const int cg = gb >> 1;
      const int colbase = cg * 16;
      const int cset = (tid >> 4) & 3;   // 4 cols each
      const int ks = tid >> 6;           // 0..7 (= wave)
      const float* wbase = Wcat + (size_t)(ks*72)*4608 + colbase + cset*4;
      for (int t = 0; t < 128; ++t) {
        if (tid < 16) {
          while (cohLoadI(&bar[(bg*16 + tid)*32]) < t) __builtin_amdgcn_s_sleep(1);
        }
        __syncthreads();
        const float* hsrc = hTx_all + (size_t)t*HTXS + (size_t)bg*16*576;
        for (int i = tid; i < 2304; i += NTHR) {   // 16b x 144 f4 (K=576)
          int bb = i / 144, q = i - bb*144;
          *(float4*)(hxs + bb*580 + q*4) = *(const float4*)(hsrc + bb*576 + q*4);
        }
        __syncthreads();
        float a0=0.f, a1=0.f, a2=0.f, a3=0.f;
        const float* hb = hxs + b*580 + ks*72;
        #pragma unroll 3
        for (int it = 0; it < 18; ++it) {
          float4 h4 = *(const float4*)(hb + it*4);
          const float* wk = wbase + (size_t)(it*4)*4608;
          float4 w0 = *(const float4*)(wk);
          float4 w1 = *(const float4*)(wk + 4608);
          float4 w2 = *(const float4*)(wk + 9216);
          float4 w3 = *(const float4*)(wk + 13824);
          a0 += h4.x*w0.x + h4.y*w1.x + h4.z*w2.x + h4.w*w3.x;
          a1 += h4.x*w0.y + h4.y*w1.y + h4.z*w2.y + h4.w*w3.y;
          a2 += h4.x*w0.z + h4.y*w1.z + h4.z*w2.z + h4.w*w3.z;
          a3 += h4.x*w0.w + h4.y*w1.w + h4.z*w2.w + h4.w*w3.w;
        }
        *(float4*)(&red[ks*256 + b*16 + cset*4]) = make_float4(a0,a1,a2,a3);
        __syncthreads();
        if (tid < 256) {                 // 16b x 16c
          float s = 0.f;
          #pragma unroll
          for (int w = 0; w < 8; ++w) s += red[w*256 + tid];
          cohStore(&oc[(size_t)(bg*16 + (tid>>4))*4608 + colbase + (tid&15)], s);
        }
        __syncthreads();                 // drain sc1 stores
        if (tid == 0) cohStoreI(&bar[1024 + gb*32], t + 1);
      }
    } else if (gb < 128) {
      // ---- def: cols [512+cg*32,+32), fp32 K=512, 4 segs x 128 ----
      const int cg = (gb - 64) >> 1;
      const int colbase = 512 + cg * 32;
      const int cset = (tid >> 4) & 7;   // 4 cols each
      const int ks = tid >> 7;           // 0..3
      const float* wbase = Wcat + (size_t)(ks*128)*4608 + colbase + cset*4;
      for (int t = 0; t < 128; ++t) {
        if (tid < 16) {
          while (cohLoadI(&bar[(bg*16 + tid)*32]) < t) __builtin_amdgcn_s_sleep(1);
        }
        __syncthreads();
        const float* hsrc = hTx_all + (size_t)t*HTXS + (size_t)bg*16*576;
        for (int i = tid; i < 2048; i += NTHR) {   // 16b x 128 f4 (K=512)
          int bb = i >> 7, q = i & 127;
          *(float4*)(hxs + bb*516 + q*4) = *(const float4*)(hsrc + bb*576 + q*4);
        }
        __syncthreads();
        float a0=0.f, a1=0.f, a2=0.f, a3=0.f;
        const float* hb = hxs + b*516 + ks*128;
        #pragma unroll 4
        for (int it = 0; it < 32; ++it) {
          float4 h4 = *(const float4*)(hb + it*4);
          const float* wk = wbase + (size_t)(it*4)*4608;
          float4 w0 = *(const float4*)(wk);
          float4 w1 = *(const float4*)(wk + 4608);
          float4 w2 = *(const float4*)(wk + 9216);
          float4 w3 = *(const float4*)(wk + 13824);
          a0 += h4.x*w0.x + h4.y*w1.x + h4.z*w2.x + h4.w*w3.x;
          a1 += h4.x*w0.y + h4.y*w1.y + h4.z*w2.y + h4.w*w3.y;
          a2 += h4.x*w0.z + h4.y*w1.z + h4.z*w2.z + h4.w*w3.z;
          a3 += h4.x*w0.w + h4.y*w1.w + h4.z*w2.w + h4.w*w3.w;
        }
        *(float4*)(&red[ks*512 + b*32 + cset*4]) = make_float4(a0,a1,a2,a3);
        __syncthreads();
        {                                 // 16b x 32c, one per thread
          float s = 0.f;
          #pragma unroll
          for (int w = 0; w < 4; ++w) s += red[w*512 + tid];
          cohStore(&oc[(size_t)(bg*16 + (tid>>5))*4608 + colbase + (tid&31)], s);
        }
        __syncthreads();                 // drain sc1 stores
        if (tid == 0) cohStoreI(&bar[1024 + gb*32], t + 1);
      }
    } else {
      // ---- late: cols [1536+cg*64,+64), bf16 K=512, 4 segs x 128 ----
      const int cg = (gb - 128) >> 1;    // 0..47 -> cols 1536..4608 (FIXED)
      const int colbase = 1536 + cg * 64;
      const int cset = (tid >> 4) & 7;   // 8 cols each
      const int ks = tid >> 7;           // 0..3
      const unsigned short* wbase = Wb16 + (size_t)(ks*128)*3072 + (colbase - 1536) + cset*8;
      for (int t = 0; t < 128; ++t) {
        if (tid < 16) {
          while (cohLoadI(&bar[(bg*16 + tid)*32]) < t) __builtin_amdgcn_s_sleep(1);
        }
        __syncthreads();
        const float* hsrc = hTx_all + (size_t)t*HTXS + (size_t)bg*16*576;
        for (int i = tid; i < 2048; i += NTHR) {
          int bb = i >> 7, q = i & 127;
          *(float4*)(hxs + bb*516 + q*4) = *(const float4*)(hsrc + bb*576 + q*4);
        }
        __syncthreads();
        float acc[8];
        #pragma unroll
        for (int j = 0; j < 8; ++j) acc[j] = 0.f;
        const float* hb = hxs + b*516 + ks*128;
        #pragma unroll 2
        for (int it = 0; it < 32; ++it) {
          float4 h4 = *(const float4*)(hb + it*4);
          float hk[4] = {h4.x, h4.y, h4.z, h4.w};
          #pragma unroll
          for (int u = 0; u < 4; ++u) {
            const uint4 wv = *(const uint4*)(wbase + (size_t)(it*4 + u)*3072);
            float f = hk[u];
            acc[0] += f*bf2f((unsigned short)(wv.x));
            acc[1] += f*bf2f((unsigned short)(wv.x >> 16));
            acc[2] += f*bf2f((unsigned short)(wv.y));
            acc[3] += f*bf2f((unsigned short)(wv.y >> 16));
            acc[4] += f*bf2f((unsigned short)(wv.z));
            acc[5] += f*bf2f((unsigned short)(wv.z >> 16));
            acc[6] += f*bf2f((unsigned short)(wv.w));
            acc[7] += f*bf2f((unsigned short)(wv.w >> 16));
          }
        }
        float* rp = &red[ks*1024 + b*64 + cset*8];
        *(float4*)(rp)     = make_float4(acc[0], acc[1], acc[2], acc[3]);
        *(float4*)(rp + 4) = make_float4(acc[4], acc[5], acc[6], acc[7]);
        __syncthreads();
        for (int i = tid; i < 1024; i += NTHR) {  // 16b x 64c
          float s = 0.f;
          #pragma unroll
          for (int w = 0; w < 4; ++w) s += red[w*1024 + i];
          cohStore(&oc[(size_t)(bg*16 + (i>>6))*4608 + colbase + (i&63)], s);
        }
        __syncthreads();                 // drain sc1 stores
        if (tid == 0) cohStoreI(&bar[1024 + gb*32], t + 1);
      }
    }
  } else {
    // ================= BC block: batch b =================
    const int b = bid;
    const int lenb = length[b];
    float hcur = 0.f;
    float usage_r = -99999.f;            // valid for tid<64
    int jprev = 0;                       // thread-0 only
    int* flg = (int*)(smem + 1100);
    const float c0r = c0[tid], c0z = c0[512 + tid], c0n = c0[1024 + tid];
    const float fc2bv = fc2_b[tid];
    const float f1b = (tid < 64) ? fc1_b[tid] : 0.f;
    const int n_ = tid & 63, kg_ = tid >> 6;
    const float* fw = fc1_w + (size_t)kg_*64*64 + n_;

    for (int t = 0; t < 128; ++t) {
      const int t32b = t*32 + b;
      // prefetch step inputs (independent of flags)
      const float* p1p = P1 + (size_t)t32b*1536;
      float p1r = p1p[tid], p1z = p1p[512 + tid], p1n = p1p[1024 + tid];
      float p2v = P2[(size_t)t32b*512 + tid];
      float uval = (tid < 64) ? u_noise[(size_t)t32b*64 + tid] : 0.f;
      // ---- wait CRIT blocks (g 0..63): argmax chain ----
      if (tid < 64) {
        while (cohLoadI(&bar[1024 + tid*32]) < t + 1) __builtin_amdgcn_s_sleep(1);
      }
      __syncthreads();
      const float* ocb = oc + (size_t)b*4608;
      float oct = cohLoad(ocb + tid);
      smem[tid] = tanhf(p2v + oct);      // th
      __syncthreads();
      {                                  // fc1 partial dots
        float sdot = 0.f;
        #pragma unroll 8
        for (int k = 0; k < 64; ++k) sdot += smem[kg_*64 + k] * fw[(size_t)k*64];
        smem[512 + tid] = sdot;
      }
      __syncthreads();
      if (tid < 64) {                    // logits + Gumbel + wave argmax
        float l = f1b;
        #pragma unroll
        for (int kg = 0; kg < 8; ++kg) l += smem[512 + kg*64 + tid];
        l += -logf(1e-20f - logf(1e-20f + uval));
        float best = l; int idx = tid;
        #pragma unroll
        for (int off = 32; off >= 1; off >>= 1) {
          float ob = __shfl_xor(best, off);
          int   oi = __shfl_xor(idx,  off);
          if (ob > best || (ob == best && oi < idx)) { best = ob; idx = oi; }
        }
        if (tid == 0) {
          flg[0] = idx;
          flg[1] = (t < 64) ? t : jprev;
          jprev = idx;
        }
      }
      // ---- wait DEF + LATE blocks (g 64..223): 160 line-spaced flags ----
      if (tid < 160) {
        while (cohLoadI(&bar[1024 + (64 + tid)*32]) < t + 1) __builtin_amdgcn_s_sleep(1);
      }
      __syncthreads();
      const int jj = flg[0], ss = flg[1];
      float vA   = cohLoad(ocb + 512  + tid);
      float vB   = cohLoad(ocb + 1024 + tid);
      float vAW0 = cohLoad(ocb + 1536 + tid);
      float vAW1 = cohLoad(ocb + 2048 + tid);
      float vAW2 = cohLoad(ocb + 2560 + tid);
      float vBW0 = cohLoad(ocb + 3072 + tid);
      float vBW1 = cohLoad(ocb + 3584 + tid);
      float vBW2 = cohLoad(ocb + 4096 + tid);
      float hnp, w0, w1, w2;
      if (jj == ss) { hnp = vA; w0 = vAW0; w1 = vAW1; w2 = vAW2; }
      else {
        hnp = hnew_part[(size_t)(b*64 + jj)*512 + tid];
        const float* wpp = whh_part + (size_t)(b*64 + jj)*1536;
        w0 = wpp[tid]; w1 = wpp[512 + tid]; w2 = wpp[1024 + tid];
      }
      float h_new = hnp + vB + fc2bv;
      float wh_r = w0 + vBW0 + c0r;
      float wh_z = w1 + vBW1 + c0z;
      float wh_n = w2 + vBW2 + c0n;
      float r  = 1.f / (1.f + expf(-(p1r + wh_r)));
      float z  = 1.f / (1.f + expf(-(p1z + wh_z)));
      float nn = tanhf(p1n + r*wh_n);
      float h1 = (1.f - z)*nn + z*h_new;
      if (t >= lenb) h1 = hcur;
      hcur = h1;
      // publish h(t+1)+lu via sc1, b-major contiguous (coalesced full lines)
      float* hw = hTx_all + (size_t)(t + 1)*HTXS + (size_t)b*576;
      cohStore(&hw[tid], h1);
      if (tid < 64) {
        float un = (usage_r - 1.f) * (tid == jj ? 0.f : 1.f);
        usage_r = un;
        cohStore(&hw[512 + tid], 1.f / (1.f + expf(-un)));
      }
      smem[tid] = h1;                    // for out projection below
      __syncthreads();                   // drain sc1 stores
      if (tid == 0) cohStoreI(&bar[b*32], t + 1);
      // ---- off critical path: slot caches + output projection ----
      hnew_part[(size_t)(b*64 + ss)*512 + tid] = vA;
      float* wps = whh_part + (size_t)(b*64 + ss)*1536;
      wps[tid] = vAW0; wps[512 + tid] = vAW1; wps[1024 + tid] = vAW2;
      {
        int a = tid & 31, jg = tid >> 5;
        float sp = 0.f;
        #pragma unroll 8
        for (int jx = 0; jx < 32; ++jx)
          sp += smem[jg*32 + jx] * fc_w[(size_t)(jg*32 + jx)*32 + a];
        smem[512 + tid] = sp;
      }
      __syncthreads();
      if (tid < 32) {
        float s2 = fc_b[tid];
        #pragma unroll
        for (int jg = 0; jg < 16; ++jg) s2 += smem[512 + jg*32 + tid];
        out[(size_t)t32b*32 + tid] = s2;
      }
    }
  }
}

// ---------------------------------------------------------------------------
extern "C" void kernel_launch(void* const* d_in, const int* in_sizes, int n_in,
                              void* d_out, int out_size, void* d_ws, size_t ws_size,
                              hipStream_t stream)
{
  const float* x      = (const float*)d_in[0];
  const int*   length = (const int*)  d_in[1];
  const float* u_nois = (const float*)d_in[2];
  const float* W_ih   = (const float*)d_in[3];
  const float* W_hh   = (const float*)d_in[4];
  const float* bias   = (const float*)d_in[5];
  const float* W_im   = (const float*)d_in[6];
  const float* W_hm   = (const float*)d_in[7];
  const float* W_um   = (const float*)d_in[8];
  const float* fc1_w  = (const float*)d_in[9];
  const float* fc1_b  = (const float*)d_in[10];
  const float* fc2_w  = (const float*)d_in[11];
  const float* fc2_b  = (const float*)d_in[12];
  const float* fc_w   = (const float*)d_in[13];
  const float* fc_b   = (const float*)d_in[14];
  float* out = (float*)d_out;

  float* ws   = (float*)d_ws;
  int*   bar  = (int*)d_ws;
  float* hTx  = ws + OFF_HTX;
  float* oc   = ws + OFF_OC;
  float* hnew = ws + OFF_HNEW;
  float* whh  = ws + OFF_WHH;
  float* c0   = ws + OFF_C0;
  float* Wcat = ws + OFF_WCAT;
  unsigned short* Wb16 = (unsigned short*)(ws + OFF_WB16);
  float* P1   = ws + OFF_P1;
  float* P2   = ws + OFF_P2;

  // zero: flag words + hTx buffer 0 (h=0, lu=0); slot caches (mem=0)
  hipMemsetAsync(d_ws, 0, (size_t)(OFF_HTX + HTXS) * sizeof(float), stream);
  hipMemsetAsync(hnew, 0, (size_t)(32*64*512 + 32*64*1536) * sizeof(float), stream);

  setup_kernel<<<2115, 512, 0, stream>>>(W_hm, fc2_w, W_um, W_hh, bias, fc2_b,
                                         Wcat, c0);

  // M_A = fc2_A@W_hh -> Wcat cols 1536:3072 ; M_B = fc2_B@W_hh -> 3072:4608
  { dim3 g(4, 24);
    gemm_f32<<<g, 256, 0, stream>>>(fc2_w,                   W_hh, nullptr, Wcat + 1536,
                                    512, 1536, 512, 512, 1536, 4608);
    gemm_f32<<<g, 256, 0, stream>>>(fc2_w + (size_t)512*512, W_hh, nullptr, Wcat + 3072,
                                    512, 1536, 512, 512, 1536, 4608); }
  // bf16 compaction of the gate-path composite weights
  cvt_kernel<<<3072, 512, 0, stream>>>(Wcat, Wb16);
  // P1 = x@W_ih + bias_ih ; P2 = x@W_im
  { dim3 g(32, 24);
    gemm_f32<<<g, 256, 0, stream>>>(x, W_ih, bias, P1, 4096, 1536, 512, 512, 1536, 1536); }
  { dim3 g(32, 8);
    gemm_f32<<<g, 256, 0, stream>>>(x, W_im, nullptr, P2, 4096, 512, 512, 512, 512, 512); }

  persist_kernel<<<NBLK, NTHR, 0, stream>>>(P1, P2, Wcat, Wb16, oc, hTx, hnew,
                                            whh, c0, fc1_w, fc1_b, fc2_b,
                                            u_nois, length, fc_w, fc_b, out, bar);
}